// Round 6
// baseline (2678.756 us; speedup 1.0000x reference)
//
#include <hip/hip_runtime.h>
#include <cstddef>

// B=64, T=512, H=256. Float inputs fp32 (runtime-detected, bf16 fallback).
// Output fp32: [out_s (B*T), out_e (B*T)].
// ws layout (bytes):
//   0        WK2   5*65536 f32  (W1f, W1fq+W1fm, W1afq+W1afm, Wr, Wh)
//   1310720  Urp   128*256 u32  (bf16 pairs along i)
//   1441792  Uhp   128*256 u32
//   1572864  qw1   64*256 f32   (b1 + q@(W1m+W1q))
//   1638400  qs    64 f32       (bs + q@Ws[0:256])
//   1638656  qe    64 f32
//   1638912  att   64*512 f32
//   1769984  g     64*512 f32
//   1901056  xrh   64*512*256 u32  (bf16(xr+br) | bf16(xh+bh)<<16)
//   35455488 ep    64*512*256 bf16 (e_outputs)
//   52232704 mode  int (0 = inputs are bf16, 1 = inputs are fp32)

static __device__ __forceinline__ float b2f(unsigned short u) {
  return __uint_as_float(((unsigned)u) << 16);
}
static __device__ __forceinline__ float blo(unsigned w) { return __uint_as_float(w << 16); }
static __device__ __forceinline__ float bhi(unsigned w) { return __uint_as_float(w & 0xffff0000u); }
static __device__ __forceinline__ unsigned short f2b(float f) {
  unsigned u = __float_as_uint(f);
  u += 0x7fffu + ((u >> 16) & 1u);  // RNE
  return (unsigned short)(u >> 16);
}
// adaptive input loads (md: 0=bf16 data, 1=fp32 data)
static __device__ __forceinline__ float ldf(const void* b, size_t i, int md) {
  return md ? ((const float*)b)[i] : b2f(((const unsigned short*)b)[i]);
}
static __device__ __forceinline__ unsigned short ldb(const void* b, size_t i, int md) {
  return md ? f2b(((const float*)b)[i]) : ((const unsigned short*)b)[i];
}
// DPP-based partial reduction (VALU pipe, not LDS pipe).
template <int CTRL>
static __device__ __forceinline__ float dpp_add(float x) {
  int v = __builtin_amdgcn_update_dpp(0, __float_as_int(x), CTRL, 0xF, 0xF, true);
  return x + __int_as_float(v);
}
// XOR-swizzled slot for packed h/rh pair index P (P in [0,128)):
// uint4-block L=P>>2, within-block s=L&3 xored with group bits -> 2-way max.
static __device__ __forceinline__ int hswz(int P) {
  int L = P >> 2, u = P & 3;
  int Ls = (L & ~3) | ((L & 3) ^ ((L >> 2) & 3));
  return Ls * 4 + u;
}

// ---------------- dtype detection ----------------
__global__ void k_detect(const void* __restrict__ fact, int* __restrict__ mode) {
  int tid = threadIdx.x;  // 256
  const unsigned short* u = (const unsigned short*)fact;
  float v = fabsf(b2f(u[2 * tid]));  // if fp32 data: low mantissa bits -> huge/NaN
  if (!(v == v)) v = 1e30f;
  for (int o = 32; o > 0; o >>= 1) v = fmaxf(v, __shfl_xor(v, o));
  __shared__ float red[4];
  int wave = tid >> 6, lane = tid & 63;
  if (lane == 0) red[wave] = v;
  __syncthreads();
  if (tid == 0) {
    float m = fmaxf(fmaxf(red[0], red[1]), fmaxf(red[2], red[3]));
    mode[0] = (m > 1e4f) ? 1 : 0;
  }
}

// ---------------- prep: combined weights + packed Ur/Uh ----------------
__global__ void k_prep_w(const void* __restrict__ W1,
                         const void* __restrict__ Wr,
                         const void* __restrict__ Wh,
                         const void* __restrict__ Ur,
                         const void* __restrict__ Uh,
                         const int* __restrict__ mode,
                         float* __restrict__ WK2,
                         unsigned* __restrict__ Urp,
                         unsigned* __restrict__ Uhp) {
  int md = *mode;
  int idx = blockIdx.x * 256 + threadIdx.x;  // 0..65535
  int i = idx >> 8, j = idx & 255;
  WK2[0 * 65536 + idx] = ldf(W1, idx, md);  // rows [0,256): f
  WK2[1 * 65536 + idx] = ldf(W1, (size_t)(768 + i) * 256 + j, md) + ldf(W1, (size_t)(1024 + i) * 256 + j, md);   // f*q
  WK2[2 * 65536 + idx] = ldf(W1, (size_t)(1280 + i) * 256 + j, md) + ldf(W1, (size_t)(1536 + i) * 256 + j, md);  // |f-q|
  WK2[3 * 65536 + idx] = ldf(Wr, idx, md);
  WK2[4 * 65536 + idx] = ldf(Wh, idx, md);
  if (i < 128) {
    Urp[idx] = (unsigned)ldb(Ur, (size_t)(2 * i) * 256 + j, md) |
               ((unsigned)ldb(Ur, (size_t)(2 * i + 1) * 256 + j, md) << 16);
    Uhp[idx] = (unsigned)ldb(Uh, (size_t)(2 * i) * 256 + j, md) |
               ((unsigned)ldb(Uh, (size_t)(2 * i + 1) * 256 + j, md) << 16);
  }
}

// ---------------- prep: q-dependent vectors ----------------
__global__ void k_prep_q(const void* __restrict__ q,
                         const void* __restrict__ W1,
                         const void* __restrict__ b1,
                         const void* __restrict__ Ws,
                         const void* __restrict__ bs,
                         const void* __restrict__ We,
                         const void* __restrict__ be,
                         const int* __restrict__ mode,
                         float* __restrict__ qw1,
                         float* __restrict__ qs,
                         float* __restrict__ qe) {
  __shared__ float qsh[256];
  __shared__ float reds[4], rede[4];
  int md = *mode;
  int b = blockIdx.x, tid = threadIdx.x;
  float qv = ldf(q, (size_t)b * 256 + tid, md);
  qsh[tid] = qv;
  __syncthreads();
  float acc = ldf(b1, tid, md);
  for (int i = 0; i < 256; ++i) {
    float w = ldf(W1, (size_t)(256 + i) * 256 + tid, md) + ldf(W1, (size_t)(512 + i) * 256 + tid, md);
    acc = fmaf(qsh[i], w, acc);
  }
  qw1[b * 256 + tid] = acc;
  float ps = qv * ldf(Ws, tid, md);
  float pe = qv * ldf(We, tid, md);
  for (int o = 32; o > 0; o >>= 1) { ps += __shfl_down(ps, o); pe += __shfl_down(pe, o); }
  int wave = tid >> 6, lane = tid & 63;
  if (lane == 0) { reds[wave] = ps; rede[wave] = pe; }
  __syncthreads();
  if (tid == 0) {
    qs[b] = ldf(bs, 0, md) + reds[0] + reds[1] + reds[2] + reds[3];
    qe[b] = ldf(be, 0, md) + rede[0] + rede[1] + rede[2] + rede[3];
  }
}

// ---------------- main GEMM: att pre-softmax + xr/xh ----------------
__launch_bounds__(256, 2)
__global__ void k_main(const void* __restrict__ fact,
                       const void* __restrict__ q,
                       const float* __restrict__ WK2,
                       const float* __restrict__ qw1,
                       const void* __restrict__ W2,
                       const void* __restrict__ b2v,
                       const void* __restrict__ br,
                       const void* __restrict__ bh,
                       const int* __restrict__ mode,
                       float* __restrict__ att,
                       unsigned* __restrict__ xrh) {
  __shared__ __align__(16) float sfT[256 * 20];  // [feature i][row r], stride 20
  __shared__ __align__(16) float sqT[256 * 20];
  __shared__ __align__(16) float saT[256 * 20];
  __shared__ float wsc[4 * 16];
  int md = *mode;
  int blk = blockIdx.x;
  int b = blk >> 5, t0 = (blk & 31) * 16;
  int tid = threadIdx.x;
  float qv = ldf(q, (size_t)b * 256 + tid, md);
  for (int r = 0; r < 16; ++r) {
    float f = ldf(fact, ((size_t)(b * 512 + t0 + r)) * 256 + tid, md);
    sfT[tid * 20 + r] = f;
    sqT[tid * 20 + r] = f * qv;
    saT[tid * 20 + r] = fabsf(f - qv);
  }
  __syncthreads();
  int jq = tid >> 2, rq = tid & 3;
  float u[4][4] = {{0}}, ar[4][4] = {{0}}, ah[4][4] = {{0}};
  const float* w0 = WK2 + jq * 4;
  const float* w1 = w0 + 65536;
  const float* w2 = w0 + 2 * 65536;
  const float* w3 = w0 + 3 * 65536;
  const float* w4 = w0 + 4 * 65536;
  for (int i = 0; i < 256; ++i) {
    float4 wf = *(const float4*)(w0 + i * 256);
    float4 wq = *(const float4*)(w1 + i * 256);
    float4 wa = *(const float4*)(w2 + i * 256);
    float4 wr4 = *(const float4*)(w3 + i * 256);
    float4 wh4 = *(const float4*)(w4 + i * 256);
    float4 s1 = *(const float4*)(sfT + i * 20 + rq * 4);
    float4 s2 = *(const float4*)(sqT + i * 20 + rq * 4);
    float4 s3 = *(const float4*)(saT + i * 20 + rq * 4);
    float s1a[4] = {s1.x, s1.y, s1.z, s1.w};
    float s2a[4] = {s2.x, s2.y, s2.z, s2.w};
    float s3a[4] = {s3.x, s3.y, s3.z, s3.w};
    float wfa[4] = {wf.x, wf.y, wf.z, wf.w};
    float wqa[4] = {wq.x, wq.y, wq.z, wq.w};
    float waa[4] = {wa.x, wa.y, wa.z, wa.w};
    float wra[4] = {wr4.x, wr4.y, wr4.z, wr4.w};
    float wha[4] = {wh4.x, wh4.y, wh4.z, wh4.w};
#pragma unroll
    for (int rr = 0; rr < 4; ++rr) {
#pragma unroll
      for (int jj = 0; jj < 4; ++jj) {
        u[rr][jj] = fmaf(s1a[rr], wfa[jj], u[rr][jj]);
        u[rr][jj] = fmaf(s2a[rr], wqa[jj], u[rr][jj]);
        u[rr][jj] = fmaf(s3a[rr], waa[jj], u[rr][jj]);
        ar[rr][jj] = fmaf(s1a[rr], wra[jj], ar[rr][jj]);
        ah[rr][jj] = fmaf(s1a[rr], wha[jj], ah[rr][jj]);
      }
    }
  }
  float qwv[4], w2v[4], brv[4], bhv[4];
#pragma unroll
  for (int jj = 0; jj < 4; ++jj) {
    int j = jq * 4 + jj;
    qwv[jj] = qw1[b * 256 + j];
    w2v[jj] = ldf(W2, j, md);
    brv[jj] = ldf(br, j, md);
    bhv[jj] = ldf(bh, j, md);
  }
  float patt[4];
#pragma unroll
  for (int rr = 0; rr < 4; ++rr) {
    float p = 0.f;
#pragma unroll
    for (int jj = 0; jj < 4; ++jj) {
      float hid = tanhf(u[rr][jj] + qwv[jj]);
      p = fmaf(hid, w2v[jj], p);
    }
    p += __shfl_down(p, 4);
    p += __shfl_down(p, 8);
    p += __shfl_down(p, 16);
    p += __shfl_down(p, 32);
    patt[rr] = p;
  }
  int wave = tid >> 6, lane = tid & 63;
  if (lane < 4) {
#pragma unroll
    for (int rr = 0; rr < 4; ++rr) wsc[wave * 16 + lane * 4 + rr] = patt[rr];
  }
  __syncthreads();
  if (tid < 16) {
    float s = wsc[tid] + wsc[16 + tid] + wsc[32 + tid] + wsc[48 + tid];
    att[b * 512 + t0 + tid] = s + ldf(b2v, 0, md);
  }
#pragma unroll
  for (int rr = 0; rr < 4; ++rr) {
    int t = t0 + rq * 4 + rr;
    unsigned vv[4];
#pragma unroll
    for (int jj = 0; jj < 4; ++jj) {
      unsigned lo = f2b(ar[rr][jj] + brv[jj]);
      unsigned hi = f2b(ah[rr][jj] + bhv[jj]);
      vv[jj] = lo | (hi << 16);
    }
    uint4 v;
    v.x = vv[0]; v.y = vv[1]; v.z = vv[2]; v.w = vv[3];
    *(uint4*)(xrh + ((size_t)(b * 512 + t)) * 256 + jq * 4) = v;
  }
}

// ---------------- softmax over T per batch ----------------
__global__ void k_softmax(const float* __restrict__ att, float* __restrict__ g) {
  __shared__ float red[8];
  int b = blockIdx.x, tid = threadIdx.x;  // 512 threads
  float v = att[b * 512 + tid];
  float m = v;
  for (int o = 32; o > 0; o >>= 1) m = fmaxf(m, __shfl_xor(m, o));
  int wave = tid >> 6, lane = tid & 63;
  if (lane == 0) red[wave] = m;
  __syncthreads();
  m = red[0];
#pragma unroll
  for (int w = 1; w < 8; ++w) m = fmaxf(m, red[w]);
  float e = __expf(v - m);
  float s = e;
  for (int o = 32; o > 0; o >>= 1) s += __shfl_xor(s, o);
  __syncthreads();
  if (lane == 0) red[wave] = s;
  __syncthreads();
  s = red[0] + red[1] + red[2] + red[3] + red[4] + red[5] + red[6] + red[7];
  g[b * 512 + tid] = e / s;
}

// ---------------- sequential GRU scan: one block per batch ----------------
// 1024 threads = 16 waves. lane = c*8+gq: gq = k-group (32 k's), c = column
// octet. Thread handles 2 columns j0=wave*16+2c, j1=j0+1 over its k-slice.
// h/rh stored in LDS as packed-bf16 pairs with XOR-swizzled uint4 layout
// (max 2-way bank aliasing = free). Cross-gq reduction via DPP (VALU pipe):
// quad_perm xor1, quad_perm xor2, row_half_mirror. Owners (gq==0) do the
// scalar nonlinearity + state writes. x staged in 32-step LDS chunks; e
// buffered in LDS, flushed every 32 steps.
__launch_bounds__(1024, 4)
__global__ void k_scan(const unsigned* __restrict__ Urp,
                       const unsigned* __restrict__ Uhp,
                       const unsigned* __restrict__ xrh,
                       const float* __restrict__ g,
                       const int* __restrict__ input_len,
                       unsigned short* __restrict__ ep) {
  __shared__ __align__(16) unsigned hp[128];    // packed bf16 h pairs (swizzled)
  __shared__ __align__(16) unsigned rhp[128];   // packed bf16 r*h pairs (swizzled)
  __shared__ float gsh[512];
  __shared__ __align__(16) unsigned xb[32 * 256];   // 32 KB: 32 steps of x
  __shared__ __align__(16) unsigned epb[32 * 128];  // 16 KB: 32 steps of e (packed pairs)
  int b = blockIdx.x, tid = threadIdx.x;
  int wave = tid >> 6, lane = tid & 63;
  int gq = lane & 7;   // k-group: k in [gq*32, gq*32+32)
  int c = lane >> 3;   // column octet
  int j0 = wave * 16 + c * 2, j1 = j0 + 1;
  int jp = wave * 8 + c;  // owned j-pair index
  // weights: k-pairs p in [gq*16, gq*16+16) for columns j0, j1 (adjacent -> uint2)
  unsigned wr0[16], wr1[16], wh0[16], wh1[16];
#pragma unroll
  for (int p = 0; p < 16; ++p) {
    uint2 wv = *(const uint2*)&Urp[(size_t)(gq * 16 + p) * 256 + j0];
    wr0[p] = wv.x; wr1[p] = wv.y;
    uint2 wv2 = *(const uint2*)&Uhp[(size_t)(gq * 16 + p) * 256 + j0];
    wh0[p] = wv2.x; wh1[p] = wv2.y;
  }
  if (tid < 512) gsh[tid] = g[b * 512 + tid];
  if (tid < 128) { hp[tid] = 0u; rhp[tid] = 0u; }
  int len = input_len[b];
  float hj0 = 0.f, hj1 = 0.f;  // owner's fp32 master state
  const uint4* xsrc = (const uint4*)(xrh + (size_t)b * 131072);
  const uint4* hp4 = (const uint4*)hp;
  const uint4* rh4 = (const uint4*)rhp;
  int hbase = gq * 4, gm = gq & 3;
  int wslot = hswz(jp);
  uint2 xc;
  __syncthreads();
  for (int t = 0; t < 512; ++t) {
    if ((t & 31) == 0) {
      uint4 v0 = xsrc[(t >> 5) * 2048 + tid];
      uint4 v1 = xsrc[(t >> 5) * 2048 + 1024 + tid];
      ((uint4*)xb)[tid] = v0;
      ((uint4*)xb)[tid + 1024] = v1;
      __syncthreads();
    }
    // ---- phase A: r-gate matvec partials ----
    float a0 = 0.f, a1 = 0.f;
#pragma unroll
    for (int i = 0; i < 4; ++i) {
      uint4 hq = hp4[hbase + (i ^ gm)];
      unsigned hw[4] = {hq.x, hq.y, hq.z, hq.w};
#pragma unroll
      for (int u2 = 0; u2 < 4; ++u2) {
        int p = i * 4 + u2;
        float hx = blo(hw[u2]), hy = bhi(hw[u2]);
        a0 = fmaf(blo(wr0[p]), hx, a0);
        a0 = fmaf(bhi(wr0[p]), hy, a0);
        a1 = fmaf(blo(wr1[p]), hx, a1);
        a1 = fmaf(bhi(wr1[p]), hy, a1);
      }
    }
    a0 = dpp_add<0xB1>(a0); a0 = dpp_add<0x4E>(a0); a0 = dpp_add<0x141>(a0);
    a1 = dpp_add<0xB1>(a1); a1 = dpp_add<0x4E>(a1); a1 = dpp_add<0x141>(a1);
    if (gq == 0) {
      xc = *(const uint2*)&xb[(t & 31) * 256 + j0];
      float r0 = 1.f / (1.f + __expf(-(a0 + blo(xc.x))));
      float r1 = 1.f / (1.f + __expf(-(a1 + blo(xc.y))));
      rhp[wslot] = (unsigned)f2b(r0 * hj0) | ((unsigned)f2b(r1 * hj1) << 16);
    }
    __syncthreads();
    // ---- phase B: candidate matvec partials ----
    float c0 = 0.f, c1 = 0.f;
#pragma unroll
    for (int i = 0; i < 4; ++i) {
      uint4 hq = rh4[hbase + (i ^ gm)];
      unsigned hw[4] = {hq.x, hq.y, hq.z, hq.w};
#pragma unroll
      for (int u2 = 0; u2 < 4; ++u2) {
        int p = i * 4 + u2;
        float hx = blo(hw[u2]), hy = bhi(hw[u2]);
        c0 = fmaf(blo(wh0[p]), hx, c0);
        c0 = fmaf(bhi(wh0[p]), hy, c0);
        c1 = fmaf(blo(wh1[p]), hx, c1);
        c1 = fmaf(bhi(wh1[p]), hy, c1);
      }
    }
    c0 = dpp_add<0xB1>(c0); c0 = dpp_add<0x4E>(c0); c0 = dpp_add<0x141>(c0);
    c1 = dpp_add<0xB1>(c1); c1 = dpp_add<0x4E>(c1); c1 = dpp_add<0x141>(c1);
    if (gq == 0) {
      float x0 = fminf(fmaxf(c0 + bhi(xc.x), -15.f), 15.f);
      float x1 = fminf(fmaxf(c1 + bhi(xc.y), -15.f), 15.f);
      float e0 = __expf(2.f * x0), e1 = __expf(2.f * x1);
      float hc0 = (e0 - 1.f) / (e0 + 1.f);
      float hc1 = (e1 - 1.f) / (e1 + 1.f);
      float gt = gsh[t];
      bool valid = t < len;
      float hn0 = hj0 + gt * (hc0 - hj0);
      float hn1 = hj1 + gt * (hc1 - hj1);
      hj0 = valid ? hn0 : hj0;
      hj1 = valid ? hn1 : hj1;
      hp[wslot] = (unsigned)f2b(hj0) | ((unsigned)f2b(hj1) << 16);
      float eo0 = valid ? hj0 : 0.f;
      float eo1 = valid ? hj1 : 0.f;
      epb[(t & 31) * 128 + jp] = (unsigned)f2b(eo0) | ((unsigned)f2b(eo1) << 16);
    }
    __syncthreads();
    if ((t & 31) == 31) {
      uint4 ev = ((const uint4*)epb)[tid];
      ((uint4*)(ep + (size_t)b * 131072 + (size_t)(t - 31) * 256))[tid] = ev;
    }
  }
}

// ---------------- final dense: out_s/out_e (fp32 output) ----------------
__global__ void k_out(const unsigned short* __restrict__ ep,
                      const void* __restrict__ Ws,
                      const void* __restrict__ We,
                      const float* __restrict__ qs,
                      const float* __restrict__ qe,
                      const int* __restrict__ mode,
                      float* __restrict__ out) {
  int md = *mode;
  int tid = threadIdx.x;
  int wave = tid >> 6, lane = tid & 63;
  int row = blockIdx.x * 4 + wave;  // (b,t) flat, 0..32767
  const unsigned short* er = ep + (size_t)row * 256 + lane * 4;
  float f0 = b2f(er[0]), f1 = b2f(er[1]), f2 = b2f(er[2]), f3 = b2f(er[3]);
  int n = 256 + lane * 4;
  float s = f0 * ldf(Ws, n, md) + f1 * ldf(Ws, n + 1, md) + f2 * ldf(Ws, n + 2, md) + f3 * ldf(Ws, n + 3, md);
  float e = f0 * ldf(We, n, md) + f1 * ldf(We, n + 1, md) + f2 * ldf(We, n + 2, md) + f3 * ldf(We, n + 3, md);
  for (int o = 32; o > 0; o >>= 1) { s += __shfl_down(s, o); e += __shfl_down(e, o); }
  if (lane == 0) {
    int b = row >> 9;
    out[row] = tanhf(qs[b] + s);
    out[32768 + row] = tanhf(qe[b] + e);
  }
}

extern "C" void kernel_launch(void* const* d_in, const int* in_sizes, int n_in,
                              void* d_out, int out_size, void* d_ws, size_t ws_size,
                              hipStream_t stream) {
  const void* q    = d_in[0];
  const void* fact = d_in[1];
  const int* ilen  = (const int*)d_in[2];
  const void* W1   = d_in[3];
  const void* b1   = d_in[4];
  const void* W2   = d_in[5];
  const void* b2v  = d_in[6];
  const void* Wr   = d_in[7];
  const void* Ur   = d_in[8];
  const void* br   = d_in[9];
  const void* Wh   = d_in[10];
  const void* Uh   = d_in[11];
  const void* bh   = d_in[12];
  const void* Ws   = d_in[13];
  const void* bs   = d_in[14];
  const void* We   = d_in[15];
  const void* be   = d_in[16];

  char* w = (char*)d_ws;
  float*    WK2 = (float*)(w);
  unsigned* Urp = (unsigned*)(w + 1310720);
  unsigned* Uhp = (unsigned*)(w + 1441792);
  float*    qw1 = (float*)(w + 1572864);
  float*    qs  = (float*)(w + 1638400);
  float*    qe  = (float*)(w + 1638656);
  float*    att = (float*)(w + 1638912);
  float*    g   = (float*)(w + 1769984);
  unsigned* xrh = (unsigned*)(w + 1901056);
  unsigned short* ep = (unsigned short*)(w + 35455488);
  int*      mode = (int*)(w + 52232704);
  float* out = (float*)d_out;

  k_detect<<<dim3(1), dim3(256), 0, stream>>>(fact, mode);
  k_prep_w<<<dim3(256), dim3(256), 0, stream>>>(W1, Wr, Wh, Ur, Uh, mode, WK2, Urp, Uhp);
  k_prep_q<<<dim3(64), dim3(256), 0, stream>>>(q, W1, b1, Ws, bs, We, be, mode, qw1, qs, qe);
  k_main<<<dim3(2048), dim3(256), 0, stream>>>(fact, q, WK2, qw1, W2, b2v, br, bh, mode, att, xrh);
  k_softmax<<<dim3(64), dim3(512), 0, stream>>>(att, g);
  k_scan<<<dim3(64), dim3(1024), 0, stream>>>(Urp, Uhp, xrh, g, ilen, ep);
  k_out<<<dim3(8192), dim3(256), 0, stream>>>(ep, Ws, We, qs, qe, mode, out);
}

// Round 7
// 2457.756 us; speedup vs baseline: 1.0899x; 1.0899x over previous
//
#include <hip/hip_runtime.h>
#include <cstddef>

// B=64, T=512, H=256. Float inputs fp32 (runtime-detected, bf16 fallback).
// Output fp32: [out_s (B*T), out_e (B*T)].
// ws layout (bytes):
//   0        WK2   5*65536 f32  (W1f, W1fq+W1fm, W1afq+W1afm, Wr, Wh)
//   1310720  Urp   128*256 u32  (bf16 pairs along i)
//   1441792  Uhp   128*256 u32
//   1572864  qw1   64*256 f32   (b1 + q@(W1m+W1q))
//   1638400  qs    64 f32       (bs + q@Ws[0:256])
//   1638656  qe    64 f32
//   1638912  att   64*512 f32
//   1769984  g     64*512 f32
//   1901056  xrh   64*512*256 u32  (bf16(xr+br) | bf16(xh+bh)<<16)
//   35455488 ep    64*512*256 bf16 (e_outputs)
//   52232704 mode  int (0 = inputs are bf16, 1 = inputs are fp32)

static __device__ __forceinline__ float b2f(unsigned short u) {
  return __uint_as_float(((unsigned)u) << 16);
}
static __device__ __forceinline__ float blo(unsigned w) { return __uint_as_float(w << 16); }
static __device__ __forceinline__ float bhi(unsigned w) { return __uint_as_float(w & 0xffff0000u); }
static __device__ __forceinline__ unsigned short f2b(float f) {
  unsigned u = __float_as_uint(f);
  u += 0x7fffu + ((u >> 16) & 1u);  // RNE
  return (unsigned short)(u >> 16);
}
// adaptive input loads (md: 0=bf16 data, 1=fp32 data)
static __device__ __forceinline__ float ldf(const void* b, size_t i, int md) {
  return md ? ((const float*)b)[i] : b2f(((const unsigned short*)b)[i]);
}
static __device__ __forceinline__ unsigned short ldb(const void* b, size_t i, int md) {
  return md ? f2b(((const float*)b)[i]) : ((const unsigned short*)b)[i];
}
// DPP-based partial reduction (VALU pipe, not LDS pipe).
template <int CTRL>
static __device__ __forceinline__ float dpp_add(float x) {
  int v = __builtin_amdgcn_update_dpp(0, __float_as_int(x), CTRL, 0xF, 0xF, true);
  return x + __int_as_float(v);
}
// full sum over each 16-lane row: xor1, xor2, xor7(half-mirror), xor15(mirror)
static __device__ __forceinline__ float red16(float x) {
  x = dpp_add<0xB1>(x);
  x = dpp_add<0x4E>(x);
  x = dpp_add<0x141>(x);
  x = dpp_add<0x140>(x);
  return x;
}

// ---------------- dtype detection ----------------
__global__ void k_detect(const void* __restrict__ fact, int* __restrict__ mode) {
  int tid = threadIdx.x;  // 256
  const unsigned short* u = (const unsigned short*)fact;
  float v = fabsf(b2f(u[2 * tid]));  // if fp32 data: low mantissa bits -> huge/NaN
  if (!(v == v)) v = 1e30f;
  for (int o = 32; o > 0; o >>= 1) v = fmaxf(v, __shfl_xor(v, o));
  __shared__ float red[4];
  int wave = tid >> 6, lane = tid & 63;
  if (lane == 0) red[wave] = v;
  __syncthreads();
  if (tid == 0) {
    float m = fmaxf(fmaxf(red[0], red[1]), fmaxf(red[2], red[3]));
    mode[0] = (m > 1e4f) ? 1 : 0;
  }
}

// ---------------- prep: combined weights + packed Ur/Uh ----------------
__global__ void k_prep_w(const void* __restrict__ W1,
                         const void* __restrict__ Wr,
                         const void* __restrict__ Wh,
                         const void* __restrict__ Ur,
                         const void* __restrict__ Uh,
                         const int* __restrict__ mode,
                         float* __restrict__ WK2,
                         unsigned* __restrict__ Urp,
                         unsigned* __restrict__ Uhp) {
  int md = *mode;
  int idx = blockIdx.x * 256 + threadIdx.x;  // 0..65535
  int i = idx >> 8, j = idx & 255;
  WK2[0 * 65536 + idx] = ldf(W1, idx, md);  // rows [0,256): f
  WK2[1 * 65536 + idx] = ldf(W1, (size_t)(768 + i) * 256 + j, md) + ldf(W1, (size_t)(1024 + i) * 256 + j, md);   // f*q
  WK2[2 * 65536 + idx] = ldf(W1, (size_t)(1280 + i) * 256 + j, md) + ldf(W1, (size_t)(1536 + i) * 256 + j, md);  // |f-q|
  WK2[3 * 65536 + idx] = ldf(Wr, idx, md);
  WK2[4 * 65536 + idx] = ldf(Wh, idx, md);
  if (i < 128) {
    Urp[idx] = (unsigned)ldb(Ur, (size_t)(2 * i) * 256 + j, md) |
               ((unsigned)ldb(Ur, (size_t)(2 * i + 1) * 256 + j, md) << 16);
    Uhp[idx] = (unsigned)ldb(Uh, (size_t)(2 * i) * 256 + j, md) |
               ((unsigned)ldb(Uh, (size_t)(2 * i + 1) * 256 + j, md) << 16);
  }
}

// ---------------- prep: q-dependent vectors ----------------
__global__ void k_prep_q(const void* __restrict__ q,
                         const void* __restrict__ W1,
                         const void* __restrict__ b1,
                         const void* __restrict__ Ws,
                         const void* __restrict__ bs,
                         const void* __restrict__ We,
                         const void* __restrict__ be,
                         const int* __restrict__ mode,
                         float* __restrict__ qw1,
                         float* __restrict__ qs,
                         float* __restrict__ qe) {
  __shared__ float qsh[256];
  __shared__ float reds[4], rede[4];
  int md = *mode;
  int b = blockIdx.x, tid = threadIdx.x;
  float qv = ldf(q, (size_t)b * 256 + tid, md);
  qsh[tid] = qv;
  __syncthreads();
  float acc = ldf(b1, tid, md);
  for (int i = 0; i < 256; ++i) {
    float w = ldf(W1, (size_t)(256 + i) * 256 + tid, md) + ldf(W1, (size_t)(512 + i) * 256 + tid, md);
    acc = fmaf(qsh[i], w, acc);
  }
  qw1[b * 256 + tid] = acc;
  float ps = qv * ldf(Ws, tid, md);
  float pe = qv * ldf(We, tid, md);
  for (int o = 32; o > 0; o >>= 1) { ps += __shfl_down(ps, o); pe += __shfl_down(pe, o); }
  int wave = tid >> 6, lane = tid & 63;
  if (lane == 0) { reds[wave] = ps; rede[wave] = pe; }
  __syncthreads();
  if (tid == 0) {
    qs[b] = ldf(bs, 0, md) + reds[0] + reds[1] + reds[2] + reds[3];
    qe[b] = ldf(be, 0, md) + rede[0] + rede[1] + rede[2] + rede[3];
  }
}

// ---------------- main GEMM: att pre-softmax + xr/xh ----------------
__launch_bounds__(256, 2)
__global__ void k_main(const void* __restrict__ fact,
                       const void* __restrict__ q,
                       const float* __restrict__ WK2,
                       const float* __restrict__ qw1,
                       const void* __restrict__ W2,
                       const void* __restrict__ b2v,
                       const void* __restrict__ br,
                       const void* __restrict__ bh,
                       const int* __restrict__ mode,
                       float* __restrict__ att,
                       unsigned* __restrict__ xrh) {
  __shared__ __align__(16) float sfT[256 * 20];  // [feature i][row r], stride 20
  __shared__ __align__(16) float sqT[256 * 20];
  __shared__ __align__(16) float saT[256 * 20];
  __shared__ float wsc[4 * 16];
  int md = *mode;
  int blk = blockIdx.x;
  int b = blk >> 5, t0 = (blk & 31) * 16;
  int tid = threadIdx.x;
  float qv = ldf(q, (size_t)b * 256 + tid, md);
  for (int r = 0; r < 16; ++r) {
    float f = ldf(fact, ((size_t)(b * 512 + t0 + r)) * 256 + tid, md);
    sfT[tid * 20 + r] = f;
    sqT[tid * 20 + r] = f * qv;
    saT[tid * 20 + r] = fabsf(f - qv);
  }
  __syncthreads();
  int jq = tid >> 2, rq = tid & 3;
  float u[4][4] = {{0}}, ar[4][4] = {{0}}, ah[4][4] = {{0}};
  const float* w0 = WK2 + jq * 4;
  const float* w1 = w0 + 65536;
  const float* w2 = w0 + 2 * 65536;
  const float* w3 = w0 + 3 * 65536;
  const float* w4 = w0 + 4 * 65536;
  for (int i = 0; i < 256; ++i) {
    float4 wf = *(const float4*)(w0 + i * 256);
    float4 wq = *(const float4*)(w1 + i * 256);
    float4 wa = *(const float4*)(w2 + i * 256);
    float4 wr4 = *(const float4*)(w3 + i * 256);
    float4 wh4 = *(const float4*)(w4 + i * 256);
    float4 s1 = *(const float4*)(sfT + i * 20 + rq * 4);
    float4 s2 = *(const float4*)(sqT + i * 20 + rq * 4);
    float4 s3 = *(const float4*)(saT + i * 20 + rq * 4);
    float s1a[4] = {s1.x, s1.y, s1.z, s1.w};
    float s2a[4] = {s2.x, s2.y, s2.z, s2.w};
    float s3a[4] = {s3.x, s3.y, s3.z, s3.w};
    float wfa[4] = {wf.x, wf.y, wf.z, wf.w};
    float wqa[4] = {wq.x, wq.y, wq.z, wq.w};
    float waa[4] = {wa.x, wa.y, wa.z, wa.w};
    float wra[4] = {wr4.x, wr4.y, wr4.z, wr4.w};
    float wha[4] = {wh4.x, wh4.y, wh4.z, wh4.w};
#pragma unroll
    for (int rr = 0; rr < 4; ++rr) {
#pragma unroll
      for (int jj = 0; jj < 4; ++jj) {
        u[rr][jj] = fmaf(s1a[rr], wfa[jj], u[rr][jj]);
        u[rr][jj] = fmaf(s2a[rr], wqa[jj], u[rr][jj]);
        u[rr][jj] = fmaf(s3a[rr], waa[jj], u[rr][jj]);
        ar[rr][jj] = fmaf(s1a[rr], wra[jj], ar[rr][jj]);
        ah[rr][jj] = fmaf(s1a[rr], wha[jj], ah[rr][jj]);
      }
    }
  }
  float qwv[4], w2v[4], brv[4], bhv[4];
#pragma unroll
  for (int jj = 0; jj < 4; ++jj) {
    int j = jq * 4 + jj;
    qwv[jj] = qw1[b * 256 + j];
    w2v[jj] = ldf(W2, j, md);
    brv[jj] = ldf(br, j, md);
    bhv[jj] = ldf(bh, j, md);
  }
  float patt[4];
#pragma unroll
  for (int rr = 0; rr < 4; ++rr) {
    float p = 0.f;
#pragma unroll
    for (int jj = 0; jj < 4; ++jj) {
      float hid = tanhf(u[rr][jj] + qwv[jj]);
      p = fmaf(hid, w2v[jj], p);
    }
    p += __shfl_down(p, 4);
    p += __shfl_down(p, 8);
    p += __shfl_down(p, 16);
    p += __shfl_down(p, 32);
    patt[rr] = p;
  }
  int wave = tid >> 6, lane = tid & 63;
  if (lane < 4) {
#pragma unroll
    for (int rr = 0; rr < 4; ++rr) wsc[wave * 16 + lane * 4 + rr] = patt[rr];
  }
  __syncthreads();
  if (tid < 16) {
    float s = wsc[tid] + wsc[16 + tid] + wsc[32 + tid] + wsc[48 + tid];
    att[b * 512 + t0 + tid] = s + ldf(b2v, 0, md);
  }
#pragma unroll
  for (int rr = 0; rr < 4; ++rr) {
    int t = t0 + rq * 4 + rr;
    unsigned vv[4];
#pragma unroll
    for (int jj = 0; jj < 4; ++jj) {
      unsigned lo = f2b(ar[rr][jj] + brv[jj]);
      unsigned hi = f2b(ah[rr][jj] + bhv[jj]);
      vv[jj] = lo | (hi << 16);
    }
    uint4 v;
    v.x = vv[0]; v.y = vv[1]; v.z = vv[2]; v.w = vv[3];
    *(uint4*)(xrh + ((size_t)(b * 512 + t)) * 256 + jq * 4) = v;
  }
}

// ---------------- softmax over T per batch ----------------
__global__ void k_softmax(const float* __restrict__ att, float* __restrict__ g) {
  __shared__ float red[8];
  int b = blockIdx.x, tid = threadIdx.x;  // 512 threads
  float v = att[b * 512 + tid];
  float m = v;
  for (int o = 32; o > 0; o >>= 1) m = fmaxf(m, __shfl_xor(m, o));
  int wave = tid >> 6, lane = tid & 63;
  if (lane == 0) red[wave] = m;
  __syncthreads();
  m = red[0];
#pragma unroll
  for (int w = 1; w < 8; ++w) m = fmaxf(m, red[w]);
  float e = __expf(v - m);
  float s = e;
  for (int o = 32; o > 0; o >>= 1) s += __shfl_xor(s, o);
  __syncthreads();
  if (lane == 0) red[wave] = s;
  __syncthreads();
  s = red[0] + red[1] + red[2] + red[3] + red[4] + red[5] + red[6] + red[7];
  g[b * 512 + tid] = e / s;
}

// ---------------- sequential GRU scan: one block per batch ----------------
// 1024 threads = 16 waves. lane = c*16+g: c = col-quad (4 cols j0=wave*16+c*4),
// g = 16-element k-slice [g*16,(g+1)*16). h/rh fp32 in LDS, 64 uint4 with XOR
// swizzle phys_u = u^(u>>3): per read instr the 16 g-addresses cover all 8
// bank-groups exactly 2x (free). Cross-g reduce via DPP row ops (VALU pipe).
// Lanes g<4 each own one column (16 parallel owners/wave). x chunk register-
// prefetched one chunk ahead; e buffered fp32 in LDS, flushed every 32 steps.
__launch_bounds__(1024, 4)
__global__ void k_scan(const unsigned* __restrict__ Urp,
                       const unsigned* __restrict__ Uhp,
                       const unsigned* __restrict__ xrh,
                       const float* __restrict__ g,
                       const int* __restrict__ input_len,
                       unsigned short* __restrict__ ep) {
  __shared__ __align__(16) float hsh[256];    // 64 uint4, swizzled
  __shared__ __align__(16) float rhsh[256];   // 64 uint4, swizzled
  __shared__ float gsh[512];
  __shared__ __align__(16) unsigned xb[8192];   // 32 KB: 32 steps of packed x
  __shared__ __align__(16) float epb[8192];     // 32 KB: 32 steps of e (fp32)
  int b = blockIdx.x, tid = threadIdx.x;
  int wave = tid >> 6, lane = tid & 63;
  int gI = lane & 15;   // k-group
  int c = lane >> 4;    // col quad
  int j0 = wave * 16 + c * 4;
  // packed bf16 weights: 8 uint4 per matrix = cols j0..j0+3, k-pairs gI*8..+7
  unsigned wrA[32], whA[32];
#pragma unroll
  for (int pp = 0; pp < 8; ++pp) {
    uint4 wv = *(const uint4*)&Urp[(size_t)(gI * 8 + pp) * 256 + j0];
    wrA[pp * 4 + 0] = wv.x; wrA[pp * 4 + 1] = wv.y;
    wrA[pp * 4 + 2] = wv.z; wrA[pp * 4 + 3] = wv.w;
    uint4 wv2 = *(const uint4*)&Uhp[(size_t)(gI * 8 + pp) * 256 + j0];
    whA[pp * 4 + 0] = wv2.x; whA[pp * 4 + 1] = wv2.y;
    whA[pp * 4 + 2] = wv2.z; whA[pp * 4 + 3] = wv2.w;
  }
  if (tid < 512) gsh[tid] = g[b * 512 + tid];
  if (tid < 64) {
    uint4 z = {0u, 0u, 0u, 0u};
    ((uint4*)hsh)[tid] = z;
    ((uint4*)rhsh)[tid] = z;
  }
  int len = input_len[b];
  int jown = j0 + gI;            // owned column when gI<4
  float hj = 0.f;                // owner master state (fp32)
  int uo = jown >> 2;
  int so = ((uo ^ (uo >> 3)) << 2) + (jown & 3);  // swizzled f32 slot
  int ru[4];
#pragma unroll
  for (int i = 0; i < 4; ++i) {
    int u = gI * 4 + i;
    ru[i] = u ^ (u >> 3);
  }
  const uint4* xsrc = (const uint4*)(xrh + (size_t)b * 131072);
  uint4 pf0 = xsrc[tid], pf1 = xsrc[1024 + tid];  // chunk 0 preload
  __syncthreads();
  const float4* h4 = (const float4*)hsh;
  const float4* rh4 = (const float4*)rhsh;
  unsigned xc = 0;
  for (int t = 0; t < 512; ++t) {
    if ((t & 31) == 0) {
      ((uint4*)xb)[tid] = pf0;
      ((uint4*)xb)[tid + 1024] = pf1;
      __syncthreads();
      if (t < 480) {  // fire-and-forget prefetch of next chunk
        pf0 = xsrc[((t >> 5) + 1) * 2048 + tid];
        pf1 = xsrc[((t >> 5) + 1) * 2048 + 1024 + tid];
      }
    }
    // ---- phase A: r-gate matvec ----
    float acc[4] = {0.f, 0.f, 0.f, 0.f};
#pragma unroll
    for (int i = 0; i < 4; ++i) {
      float4 hv = h4[ru[i]];
#pragma unroll
      for (int cc = 0; cc < 4; ++cc) {
        unsigned w0 = wrA[(2 * i) * 4 + cc];
        unsigned w1 = wrA[(2 * i + 1) * 4 + cc];
        acc[cc] = fmaf(blo(w0), hv.x, acc[cc]);
        acc[cc] = fmaf(bhi(w0), hv.y, acc[cc]);
        acc[cc] = fmaf(blo(w1), hv.z, acc[cc]);
        acc[cc] = fmaf(bhi(w1), hv.w, acc[cc]);
      }
    }
#pragma unroll
    for (int cc = 0; cc < 4; ++cc) acc[cc] = red16(acc[cc]);
    if (gI < 4) {
      float asel = (gI & 2) ? ((gI & 1) ? acc[3] : acc[2])
                            : ((gI & 1) ? acc[1] : acc[0]);
      xc = xb[(t & 31) * 256 + jown];
      float r = 1.f / (1.f + __expf(-(asel + blo(xc))));
      rhsh[so] = r * hj;
    }
    __syncthreads();
    // ---- phase B: candidate matvec ----
    float cac[4] = {0.f, 0.f, 0.f, 0.f};
#pragma unroll
    for (int i = 0; i < 4; ++i) {
      float4 rv = rh4[ru[i]];
#pragma unroll
      for (int cc = 0; cc < 4; ++cc) {
        unsigned w0 = whA[(2 * i) * 4 + cc];
        unsigned w1 = whA[(2 * i + 1) * 4 + cc];
        cac[cc] = fmaf(blo(w0), rv.x, cac[cc]);
        cac[cc] = fmaf(bhi(w0), rv.y, cac[cc]);
        cac[cc] = fmaf(blo(w1), rv.z, cac[cc]);
        cac[cc] = fmaf(bhi(w1), rv.w, cac[cc]);
      }
    }
#pragma unroll
    for (int cc = 0; cc < 4; ++cc) cac[cc] = red16(cac[cc]);
    if (gI < 4) {
      float csel = (gI & 2) ? ((gI & 1) ? cac[3] : cac[2])
                            : ((gI & 1) ? cac[1] : cac[0]);
      float xcl = fminf(fmaxf(csel + bhi(xc), -15.f), 15.f);
      float exv = __expf(2.f * xcl);
      float hc = (exv - 1.f) / (exv + 1.f);
      float gt = gsh[t];
      bool valid = t < len;
      float hn = hj + gt * (hc - hj);
      hj = valid ? hn : hj;
      hsh[so] = hj;
      epb[(t & 31) * 256 + jown] = valid ? hj : 0.f;
    }
    __syncthreads();
    if ((t & 31) == 31) {
      float4 e0 = ((const float4*)epb)[tid * 2];
      float4 e1 = ((const float4*)epb)[tid * 2 + 1];
      uint4 o;
      o.x = (unsigned)f2b(e0.x) | ((unsigned)f2b(e0.y) << 16);
      o.y = (unsigned)f2b(e0.z) | ((unsigned)f2b(e0.w) << 16);
      o.z = (unsigned)f2b(e1.x) | ((unsigned)f2b(e1.y) << 16);
      o.w = (unsigned)f2b(e1.z) | ((unsigned)f2b(e1.w) << 16);
      ((uint4*)(ep + (size_t)b * 131072 + (size_t)(t - 31) * 256))[tid] = o;
    }
  }
}

// ---------------- final dense: out_s/out_e (fp32 output) ----------------
__global__ void k_out(const unsigned short* __restrict__ ep,
                      const void* __restrict__ Ws,
                      const void* __restrict__ We,
                      const float* __restrict__ qs,
                      const float* __restrict__ qe,
                      const int* __restrict__ mode,
                      float* __restrict__ out) {
  int md = *mode;
  int tid = threadIdx.x;
  int wave = tid >> 6, lane = tid & 63;
  int row = blockIdx.x * 4 + wave;  // (b,t) flat, 0..32767
  const unsigned short* er = ep + (size_t)row * 256 + lane * 4;
  float f0 = b2f(er[0]), f1 = b2f(er[1]), f2 = b2f(er[2]), f3 = b2f(er[3]);
  int n = 256 + lane * 4;
  float s = f0 * ldf(Ws, n, md) + f1 * ldf(Ws, n + 1, md) + f2 * ldf(Ws, n + 2, md) + f3 * ldf(Ws, n + 3, md);
  float e = f0 * ldf(We, n, md) + f1 * ldf(We, n + 1, md) + f2 * ldf(We, n + 2, md) + f3 * ldf(We, n + 3, md);
  for (int o = 32; o > 0; o >>= 1) { s += __shfl_down(s, o); e += __shfl_down(e, o); }
  if (lane == 0) {
    int b = row >> 9;
    out[row] = tanhf(qs[b] + s);
    out[32768 + row] = tanhf(qe[b] + e);
  }
}

extern "C" void kernel_launch(void* const* d_in, const int* in_sizes, int n_in,
                              void* d_out, int out_size, void* d_ws, size_t ws_size,
                              hipStream_t stream) {
  const void* q    = d_in[0];
  const void* fact = d_in[1];
  const int* ilen  = (const int*)d_in[2];
  const void* W1   = d_in[3];
  const void* b1   = d_in[4];
  const void* W2   = d_in[5];
  const void* b2v  = d_in[6];
  const void* Wr   = d_in[7];
  const void* Ur   = d_in[8];
  const void* br   = d_in[9];
  const void* Wh   = d_in[10];
  const void* Uh   = d_in[11];
  const void* bh   = d_in[12];
  const void* Ws   = d_in[13];
  const void* bs   = d_in[14];
  const void* We   = d_in[15];
  const void* be   = d_in[16];

  char* w = (char*)d_ws;
  float*    WK2 = (float*)(w);
  unsigned* Urp = (unsigned*)(w + 1310720);
  unsigned* Uhp = (unsigned*)(w + 1441792);
  float*    qw1 = (float*)(w + 1572864);
  float*    qs  = (float*)(w + 1638400);
  float*    qe  = (float*)(w + 1638656);
  float*    att = (float*)(w + 1638912);
  float*    g   = (float*)(w + 1769984);
  unsigned* xrh = (unsigned*)(w + 1901056);
  unsigned short* ep = (unsigned short*)(w + 35455488);
  int*      mode = (int*)(w + 52232704);
  float* out = (float*)d_out;

  k_detect<<<dim3(1), dim3(256), 0, stream>>>(fact, mode);
  k_prep_w<<<dim3(256), dim3(256), 0, stream>>>(W1, Wr, Wh, Ur, Uh, mode, WK2, Urp, Uhp);
  k_prep_q<<<dim3(64), dim3(256), 0, stream>>>(q, W1, b1, Ws, bs, We, be, mode, qw1, qs, qe);
  k_main<<<dim3(2048), dim3(256), 0, stream>>>(fact, q, WK2, qw1, W2, b2v, br, bh, mode, att, xrh);
  k_softmax<<<dim3(64), dim3(512), 0, stream>>>(att, g);
  k_scan<<<dim3(64), dim3(1024), 0, stream>>>(Urp, Uhp, xrh, g, ilen, ep);
  k_out<<<dim3(8192), dim3(256), 0, stream>>>(ep, Ws, We, qs, qe, mode, out);
}

// Round 8
// 1455.075 us; speedup vs baseline: 1.8410x; 1.6891x over previous
//
#include <hip/hip_runtime.h>
#include <cstddef>

// B=64, T=512, H=256. Float inputs fp32 (runtime-detected, bf16 fallback).
// Output fp32: [out_s (B*T), out_e (B*T)].
// ws layout (bytes):
//   0        WK2   5*65536 f32  (W1f, W1fq+W1fm, W1afq+W1afm, Wr, Wh)
//   1310720  Urp   128*256 u32  (bf16 pairs along i)
//   1441792  Uhp   128*256 u32
//   1572864  qw1   64*256 f32   (b1 + q@(W1m+W1q))
//   1638400  qs    64 f32       (bs + q@Ws[0:256])
//   1638656  qe    64 f32
//   1638912  att   64*512 f32
//   1769984  g     64*512 f32
//   1901056  xrh   64*512*256 u32  (bf16(xr+br) | bf16(xh+bh)<<16)
//   35455488 ep    64*512*256 bf16 (e_outputs)
//   52232704 mode  int (0 = inputs are bf16, 1 = inputs are fp32)

static __device__ __forceinline__ float b2f(unsigned short u) {
  return __uint_as_float(((unsigned)u) << 16);
}
static __device__ __forceinline__ float blo(unsigned w) { return __uint_as_float(w << 16); }
static __device__ __forceinline__ float bhi(unsigned w) { return __uint_as_float(w & 0xffff0000u); }
static __device__ __forceinline__ unsigned short f2b(float f) {
  unsigned u = __float_as_uint(f);
  u += 0x7fffu + ((u >> 16) & 1u);  // RNE
  return (unsigned short)(u >> 16);
}
// adaptive input loads (md: 0=bf16 data, 1=fp32 data)
static __device__ __forceinline__ float ldf(const void* b, size_t i, int md) {
  return md ? ((const float*)b)[i] : b2f(((const unsigned short*)b)[i]);
}
static __device__ __forceinline__ unsigned short ldb(const void* b, size_t i, int md) {
  return md ? f2b(((const float*)b)[i]) : ((const unsigned short*)b)[i];
}
// packed bf16 pair dot product with fp32 accumulate
#if defined(__has_builtin)
#if __has_builtin(__builtin_amdgcn_fdot2_f32_bf16)
#define USE_DOT2 1
#endif
#endif
#ifdef USE_DOT2
typedef __bf16 bf16x2_t __attribute__((ext_vector_type(2)));
static __device__ __forceinline__ float dot2p(unsigned a, unsigned b, float c) {
  return __builtin_amdgcn_fdot2_f32_bf16(__builtin_bit_cast(bf16x2_t, a),
                                         __builtin_bit_cast(bf16x2_t, b), c, false);
}
#else
static __device__ __forceinline__ float dot2p(unsigned a, unsigned b, float c) {
  c = fmaf(blo(a), blo(b), c);
  return fmaf(bhi(a), bhi(b), c);
}
#endif
// DPP-based partial reduction (VALU pipe, not LDS pipe).
template <int CTRL>
static __device__ __forceinline__ float dpp_add(float x) {
  int v = __builtin_amdgcn_update_dpp(0, __float_as_int(x), CTRL, 0xF, 0xF, true);
  return x + __int_as_float(v);
}
// full sum over each 16-lane row: xor1, xor2, xor7(half-mirror), xor15(mirror)
static __device__ __forceinline__ float red16(float x) {
  x = dpp_add<0xB1>(x);
  x = dpp_add<0x4E>(x);
  x = dpp_add<0x141>(x);
  x = dpp_add<0x140>(x);
  return x;
}
// XOR-swizzled physical u32 index for logical packed-pair index p in [0,128):
// uint4 slot s=p>>2 -> s ^ (s>>2). Both per-phase read address-sets cover all
// 8 bank-groups exactly 2x (enumerated) = free.
static __device__ __forceinline__ int pswz(int p) {
  int s = p >> 2;
  return (((s ^ (s >> 2)) << 2) | (p & 3));
}

// ---------------- dtype detection ----------------
__global__ void k_detect(const void* __restrict__ fact, int* __restrict__ mode) {
  int tid = threadIdx.x;  // 256
  const unsigned short* u = (const unsigned short*)fact;
  float v = fabsf(b2f(u[2 * tid]));  // if fp32 data: low mantissa bits -> huge/NaN
  if (!(v == v)) v = 1e30f;
  for (int o = 32; o > 0; o >>= 1) v = fmaxf(v, __shfl_xor(v, o));
  __shared__ float red[4];
  int wave = tid >> 6, lane = tid & 63;
  if (lane == 0) red[wave] = v;
  __syncthreads();
  if (tid == 0) {
    float m = fmaxf(fmaxf(red[0], red[1]), fmaxf(red[2], red[3]));
    mode[0] = (m > 1e4f) ? 1 : 0;
  }
}

// ---------------- prep: combined weights + packed Ur/Uh ----------------
__global__ void k_prep_w(const void* __restrict__ W1,
                         const void* __restrict__ Wr,
                         const void* __restrict__ Wh,
                         const void* __restrict__ Ur,
                         const void* __restrict__ Uh,
                         const int* __restrict__ mode,
                         float* __restrict__ WK2,
                         unsigned* __restrict__ Urp,
                         unsigned* __restrict__ Uhp) {
  int md = *mode;
  int idx = blockIdx.x * 256 + threadIdx.x;  // 0..65535
  int i = idx >> 8, j = idx & 255;
  WK2[0 * 65536 + idx] = ldf(W1, idx, md);  // rows [0,256): f
  WK2[1 * 65536 + idx] = ldf(W1, (size_t)(768 + i) * 256 + j, md) + ldf(W1, (size_t)(1024 + i) * 256 + j, md);   // f*q
  WK2[2 * 65536 + idx] = ldf(W1, (size_t)(1280 + i) * 256 + j, md) + ldf(W1, (size_t)(1536 + i) * 256 + j, md);  // |f-q|
  WK2[3 * 65536 + idx] = ldf(Wr, idx, md);
  WK2[4 * 65536 + idx] = ldf(Wh, idx, md);
  if (i < 128) {
    Urp[idx] = (unsigned)ldb(Ur, (size_t)(2 * i) * 256 + j, md) |
               ((unsigned)ldb(Ur, (size_t)(2 * i + 1) * 256 + j, md) << 16);
    Uhp[idx] = (unsigned)ldb(Uh, (size_t)(2 * i) * 256 + j, md) |
               ((unsigned)ldb(Uh, (size_t)(2 * i + 1) * 256 + j, md) << 16);
  }
}

// ---------------- prep: q-dependent vectors ----------------
__global__ void k_prep_q(const void* __restrict__ q,
                         const void* __restrict__ W1,
                         const void* __restrict__ b1,
                         const void* __restrict__ Ws,
                         const void* __restrict__ bs,
                         const void* __restrict__ We,
                         const void* __restrict__ be,
                         const int* __restrict__ mode,
                         float* __restrict__ qw1,
                         float* __restrict__ qs,
                         float* __restrict__ qe) {
  __shared__ float qsh[256];
  __shared__ float reds[4], rede[4];
  int md = *mode;
  int b = blockIdx.x, tid = threadIdx.x;
  float qv = ldf(q, (size_t)b * 256 + tid, md);
  qsh[tid] = qv;
  __syncthreads();
  float acc = ldf(b1, tid, md);
  for (int i = 0; i < 256; ++i) {
    float w = ldf(W1, (size_t)(256 + i) * 256 + tid, md) + ldf(W1, (size_t)(512 + i) * 256 + tid, md);
    acc = fmaf(qsh[i], w, acc);
  }
  qw1[b * 256 + tid] = acc;
  float ps = qv * ldf(Ws, tid, md);
  float pe = qv * ldf(We, tid, md);
  for (int o = 32; o > 0; o >>= 1) { ps += __shfl_down(ps, o); pe += __shfl_down(pe, o); }
  int wave = tid >> 6, lane = tid & 63;
  if (lane == 0) { reds[wave] = ps; rede[wave] = pe; }
  __syncthreads();
  if (tid == 0) {
    qs[b] = ldf(bs, 0, md) + reds[0] + reds[1] + reds[2] + reds[3];
    qe[b] = ldf(be, 0, md) + rede[0] + rede[1] + rede[2] + rede[3];
  }
}

// ---------------- main GEMM: att pre-softmax + xr/xh ----------------
__launch_bounds__(256, 2)
__global__ void k_main(const void* __restrict__ fact,
                       const void* __restrict__ q,
                       const float* __restrict__ WK2,
                       const float* __restrict__ qw1,
                       const void* __restrict__ W2,
                       const void* __restrict__ b2v,
                       const void* __restrict__ br,
                       const void* __restrict__ bh,
                       const int* __restrict__ mode,
                       float* __restrict__ att,
                       unsigned* __restrict__ xrh) {
  __shared__ __align__(16) float sfT[256 * 20];  // [feature i][row r], stride 20
  __shared__ __align__(16) float sqT[256 * 20];
  __shared__ __align__(16) float saT[256 * 20];
  __shared__ float wsc[4 * 16];
  int md = *mode;
  int blk = blockIdx.x;
  int b = blk >> 5, t0 = (blk & 31) * 16;
  int tid = threadIdx.x;
  float qv = ldf(q, (size_t)b * 256 + tid, md);
  for (int r = 0; r < 16; ++r) {
    float f = ldf(fact, ((size_t)(b * 512 + t0 + r)) * 256 + tid, md);
    sfT[tid * 20 + r] = f;
    sqT[tid * 20 + r] = f * qv;
    saT[tid * 20 + r] = fabsf(f - qv);
  }
  __syncthreads();
  int jq = tid >> 2, rq = tid & 3;
  float u[4][4] = {{0}}, ar[4][4] = {{0}}, ah[4][4] = {{0}};
  const float* w0 = WK2 + jq * 4;
  const float* w1 = w0 + 65536;
  const float* w2 = w0 + 2 * 65536;
  const float* w3 = w0 + 3 * 65536;
  const float* w4 = w0 + 4 * 65536;
  for (int i = 0; i < 256; ++i) {
    float4 wf = *(const float4*)(w0 + i * 256);
    float4 wq = *(const float4*)(w1 + i * 256);
    float4 wa = *(const float4*)(w2 + i * 256);
    float4 wr4 = *(const float4*)(w3 + i * 256);
    float4 wh4 = *(const float4*)(w4 + i * 256);
    float4 s1 = *(const float4*)(sfT + i * 20 + rq * 4);
    float4 s2 = *(const float4*)(sqT + i * 20 + rq * 4);
    float4 s3 = *(const float4*)(saT + i * 20 + rq * 4);
    float s1a[4] = {s1.x, s1.y, s1.z, s1.w};
    float s2a[4] = {s2.x, s2.y, s2.z, s2.w};
    float s3a[4] = {s3.x, s3.y, s3.z, s3.w};
    float wfa[4] = {wf.x, wf.y, wf.z, wf.w};
    float wqa[4] = {wq.x, wq.y, wq.z, wq.w};
    float waa[4] = {wa.x, wa.y, wa.z, wa.w};
    float wra[4] = {wr4.x, wr4.y, wr4.z, wr4.w};
    float wha[4] = {wh4.x, wh4.y, wh4.z, wh4.w};
#pragma unroll
    for (int rr = 0; rr < 4; ++rr) {
#pragma unroll
      for (int jj = 0; jj < 4; ++jj) {
        u[rr][jj] = fmaf(s1a[rr], wfa[jj], u[rr][jj]);
        u[rr][jj] = fmaf(s2a[rr], wqa[jj], u[rr][jj]);
        u[rr][jj] = fmaf(s3a[rr], waa[jj], u[rr][jj]);
        ar[rr][jj] = fmaf(s1a[rr], wra[jj], ar[rr][jj]);
        ah[rr][jj] = fmaf(s1a[rr], wha[jj], ah[rr][jj]);
      }
    }
  }
  float qwv[4], w2v[4], brv[4], bhv[4];
#pragma unroll
  for (int jj = 0; jj < 4; ++jj) {
    int j = jq * 4 + jj;
    qwv[jj] = qw1[b * 256 + j];
    w2v[jj] = ldf(W2, j, md);
    brv[jj] = ldf(br, j, md);
    bhv[jj] = ldf(bh, j, md);
  }
  float patt[4];
#pragma unroll
  for (int rr = 0; rr < 4; ++rr) {
    float p = 0.f;
#pragma unroll
    for (int jj = 0; jj < 4; ++jj) {
      float hid = tanhf(u[rr][jj] + qwv[jj]);
      p = fmaf(hid, w2v[jj], p);
    }
    p += __shfl_down(p, 4);
    p += __shfl_down(p, 8);
    p += __shfl_down(p, 16);
    p += __shfl_down(p, 32);
    patt[rr] = p;
  }
  int wave = tid >> 6, lane = tid & 63;
  if (lane < 4) {
#pragma unroll
    for (int rr = 0; rr < 4; ++rr) wsc[wave * 16 + lane * 4 + rr] = patt[rr];
  }
  __syncthreads();
  if (tid < 16) {
    float s = wsc[tid] + wsc[16 + tid] + wsc[32 + tid] + wsc[48 + tid];
    att[b * 512 + t0 + tid] = s + ldf(b2v, 0, md);
  }
#pragma unroll
  for (int rr = 0; rr < 4; ++rr) {
    int t = t0 + rq * 4 + rr;
    unsigned vv[4];
#pragma unroll
    for (int jj = 0; jj < 4; ++jj) {
      unsigned lo = f2b(ar[rr][jj] + brv[jj]);
      unsigned hi = f2b(ah[rr][jj] + bhv[jj]);
      vv[jj] = lo | (hi << 16);
    }
    uint4 v;
    v.x = vv[0]; v.y = vv[1]; v.z = vv[2]; v.w = vv[3];
    *(uint4*)(xrh + ((size_t)(b * 512 + t)) * 256 + jq * 4) = v;
  }
}

// ---------------- softmax over T per batch ----------------
__global__ void k_softmax(const float* __restrict__ att, float* __restrict__ g) {
  __shared__ float red[8];
  int b = blockIdx.x, tid = threadIdx.x;  // 512 threads
  float v = att[b * 512 + tid];
  float m = v;
  for (int o = 32; o > 0; o >>= 1) m = fmaxf(m, __shfl_xor(m, o));
  int wave = tid >> 6, lane = tid & 63;
  if (lane == 0) red[wave] = m;
  __syncthreads();
  m = red[0];
#pragma unroll
  for (int w = 1; w < 8; ++w) m = fmaxf(m, red[w]);
  float e = __expf(v - m);
  float s = e;
  for (int o = 32; o > 0; o >>= 1) s += __shfl_xor(s, o);
  __syncthreads();
  if (lane == 0) red[wave] = s;
  __syncthreads();
  s = red[0] + red[1] + red[2] + red[3] + red[4] + red[5] + red[6] + red[7];
  g[b * 512 + tid] = e / s;
}

// ---------------- sequential GRU scan: one block per batch ----------------
// 1024 threads = 16 waves. lane = c*16+gI: c = col-quad (4 cols j0=wave*16+c*4),
// gI = 16-element k-slice. h/rh in LDS as PACKED bf16 pairs (128 u32), XOR-
// swizzled uint4 slots (s^(s>>2): both per-phase read sets cover 8 bank-groups
// exactly 2x = free). Inner product via v_dot2_f32_bf16 (packed, no unpacks).
// Cross-gI reduce via DPP (VALU pipe). Owners gI<2 finalize 2 cols each (u32
// packed writes). x chunk register-prefetched; e packed in LDS, flushed every
// 32 steps with contiguous stride-16B reads (0-conflict pattern).
__launch_bounds__(1024, 4)
__global__ void k_scan(const unsigned* __restrict__ Urp,
                       const unsigned* __restrict__ Uhp,
                       const unsigned* __restrict__ xrh,
                       const float* __restrict__ g,
                       const int* __restrict__ input_len,
                       unsigned short* __restrict__ ep) {
  __shared__ __align__(16) unsigned hp[128];    // packed bf16 h pairs, swizzled
  __shared__ __align__(16) unsigned rhp[128];   // packed bf16 r*h pairs, swizzled
  __shared__ float gsh[512];
  __shared__ __align__(16) unsigned xb[8192];   // 32 KB: 32 steps of packed x
  __shared__ __align__(16) unsigned epb[4096];  // 16 KB: 32 steps of packed e
  int b = blockIdx.x, tid = threadIdx.x;
  int wave = tid >> 6, lane = tid & 63;
  int gI = lane & 15;   // k-slice [gI*16,(gI+1)*16) = pairs [gI*8, gI*8+8)
  int c = lane >> 4;    // col quad
  int j0 = wave * 16 + c * 4;
  // packed bf16 weights: cols j0..j0+3, k-pairs gI*8..+7 (8 uint4 each matrix)
  unsigned wrA[32], whA[32];
#pragma unroll
  for (int pp = 0; pp < 8; ++pp) {
    uint4 wv = *(const uint4*)&Urp[(size_t)(gI * 8 + pp) * 256 + j0];
    wrA[pp * 4 + 0] = wv.x; wrA[pp * 4 + 1] = wv.y;
    wrA[pp * 4 + 2] = wv.z; wrA[pp * 4 + 3] = wv.w;
    uint4 wv2 = *(const uint4*)&Uhp[(size_t)(gI * 8 + pp) * 256 + j0];
    whA[pp * 4 + 0] = wv2.x; whA[pp * 4 + 1] = wv2.y;
    whA[pp * 4 + 2] = wv2.z; whA[pp * 4 + 3] = wv2.w;
  }
  if (tid < 512) gsh[tid] = g[b * 512 + tid];
  if (tid < 32) {
    uint4 z = {0u, 0u, 0u, 0u};
    ((uint4*)hp)[tid] = z;
    ((uint4*)rhp)[tid] = z;
  }
  int len = input_len[b];
  // owner lanes gI<2: own packed pair pj = j0/2 + gI (cols 2pj, 2pj+1)
  int pj = (j0 >> 1) + gI;
  int wp = pswz(pj);             // swizzled u32 slot for owner writes
  float hj0 = 0.f, hj1 = 0.f;    // owner master state (fp32)
  // phys uint4 slots for this thread's 2 h reads (slots 2gI, 2gI+1)
  int hs0 = (2 * gI) ^ ((2 * gI) >> 2);
  int hs1 = (2 * gI + 1) ^ ((2 * gI + 1) >> 2);
  const uint4* xsrc = (const uint4*)(xrh + (size_t)b * 131072);
  uint4 pf0 = xsrc[tid], pf1 = xsrc[1024 + tid];  // chunk 0 preload
  __syncthreads();
  const uint4* hp4 = (const uint4*)hp;
  const uint4* rh4 = (const uint4*)rhp;
  uint2 xc2 = {0u, 0u};
  for (int t = 0; t < 512; ++t) {
    if ((t & 31) == 0) {
      ((uint4*)xb)[tid] = pf0;
      ((uint4*)xb)[tid + 1024] = pf1;
      __syncthreads();
      if (t < 480) {  // fire-and-forget prefetch of next chunk
        pf0 = xsrc[((t >> 5) + 1) * 2048 + tid];
        pf1 = xsrc[((t >> 5) + 1) * 2048 + 1024 + tid];
      }
    }
    // ---- phase A: r-gate matvec (packed dot2) ----
    float acc[4] = {0.f, 0.f, 0.f, 0.f};
    {
      uint4 h0 = hp4[hs0], h1 = hp4[hs1];
      unsigned hw[8] = {h0.x, h0.y, h0.z, h0.w, h1.x, h1.y, h1.z, h1.w};
#pragma unroll
      for (int pp = 0; pp < 8; ++pp) {
#pragma unroll
        for (int cc = 0; cc < 4; ++cc)
          acc[cc] = dot2p(wrA[pp * 4 + cc], hw[pp], acc[cc]);
      }
    }
#pragma unroll
    for (int cc = 0; cc < 4; ++cc) acc[cc] = red16(acc[cc]);
    if (gI < 2) {
      xc2 = *(const uint2*)&xb[(t & 31) * 256 + 2 * pj];
      float sa = gI ? acc[2] : acc[0];
      float sb = gI ? acc[3] : acc[1];
      float r0 = 1.f / (1.f + __expf(-(sa + blo(xc2.x))));
      float r1 = 1.f / (1.f + __expf(-(sb + blo(xc2.y))));
      rhp[wp] = (unsigned)f2b(r0 * hj0) | ((unsigned)f2b(r1 * hj1) << 16);
    }
    __syncthreads();
    // ---- phase B: candidate matvec (packed dot2) ----
    float cac[4] = {0.f, 0.f, 0.f, 0.f};
    {
      uint4 h0 = rh4[hs0], h1 = rh4[hs1];
      unsigned hw[8] = {h0.x, h0.y, h0.z, h0.w, h1.x, h1.y, h1.z, h1.w};
#pragma unroll
      for (int pp = 0; pp < 8; ++pp) {
#pragma unroll
        for (int cc = 0; cc < 4; ++cc)
          cac[cc] = dot2p(whA[pp * 4 + cc], hw[pp], cac[cc]);
      }
    }
#pragma unroll
    for (int cc = 0; cc < 4; ++cc) cac[cc] = red16(cac[cc]);
    if (gI < 2) {
      float sa = gI ? cac[2] : cac[0];
      float sb = gI ? cac[3] : cac[1];
      float x0 = fminf(fmaxf(sa + bhi(xc2.x), -15.f), 15.f);
      float x1 = fminf(fmaxf(sb + bhi(xc2.y), -15.f), 15.f);
      float e0 = __expf(2.f * x0), e1 = __expf(2.f * x1);
      float hc0 = (e0 - 1.f) / (e0 + 1.f);
      float hc1 = (e1 - 1.f) / (e1 + 1.f);
      float gt = gsh[t];
      bool valid = t < len;
      float hn0 = hj0 + gt * (hc0 - hj0);
      float hn1 = hj1 + gt * (hc1 - hj1);
      hj0 = valid ? hn0 : hj0;
      hj1 = valid ? hn1 : hj1;
      hp[wp] = (unsigned)f2b(hj0) | ((unsigned)f2b(hj1) << 16);
      float eo0 = valid ? hj0 : 0.f;
      float eo1 = valid ? hj1 : 0.f;
      epb[(t & 31) * 128 + pj] = (unsigned)f2b(eo0) | ((unsigned)f2b(eo1) << 16);
    }
    __syncthreads();
    if ((t & 31) == 31) {
      // contiguous stride-16B flush (0-conflict pattern, round-5 verified)
      uint4 ev = ((const uint4*)epb)[tid >= 1024 ? 0 : tid];
      int step = tid >> 5, m = tid & 31;
      ((uint4*)(ep + (size_t)b * 131072 + (size_t)(t - 31 + step) * 256))[m] = ev;
    }
  }
}

// ---------------- final dense: out_s/out_e (fp32 output) ----------------
__global__ void k_out(const unsigned short* __restrict__ ep,
                      const void* __restrict__ Ws,
                      const void* __restrict__ We,
                      const float* __restrict__ qs,
                      const float* __restrict__ qe,
                      const int* __restrict__ mode,
                      float* __restrict__ out) {
  int md = *mode;
  int tid = threadIdx.x;
  int wave = tid >> 6, lane = tid & 63;
  int row = blockIdx.x * 4 + wave;  // (b,t) flat, 0..32767
  const unsigned short* er = ep + (size_t)row * 256 + lane * 4;
  float f0 = b2f(er[0]), f1 = b2f(er[1]), f2 = b2f(er[2]), f3 = b2f(er[3]);
  int n = 256 + lane * 4;
  float s = f0 * ldf(Ws, n, md) + f1 * ldf(Ws, n + 1, md) + f2 * ldf(Ws, n + 2, md) + f3 * ldf(Ws, n + 3, md);
  float e = f0 * ldf(We, n, md) + f1 * ldf(We, n + 1, md) + f2 * ldf(We, n + 2, md) + f3 * ldf(We, n + 3, md);
  for (int o = 32; o > 0; o >>= 1) { s += __shfl_down(s, o); e += __shfl_down(e, o); }
  if (lane == 0) {
    int b = row >> 9;
    out[row] = tanhf(qs[b] + s);
    out[32768 + row] = tanhf(qe[b] + e);
  }
}

extern "C" void kernel_launch(void* const* d_in, const int* in_sizes, int n_in,
                              void* d_out, int out_size, void* d_ws, size_t ws_size,
                              hipStream_t stream) {
  const void* q    = d_in[0];
  const void* fact = d_in[1];
  const int* ilen  = (const int*)d_in[2];
  const void* W1   = d_in[3];
  const void* b1   = d_in[4];
  const void* W2   = d_in[5];
  const void* b2v  = d_in[6];
  const void* Wr   = d_in[7];
  const void* Ur   = d_in[8];
  const void* br   = d_in[9];
  const void* Wh   = d_in[10];
  const void* Uh   = d_in[11];
  const void* bh   = d_in[12];
  const void* Ws   = d_in[13];
  const void* bs   = d_in[14];
  const void* We   = d_in[15];
  const void* be   = d_in[16];

  char* w = (char*)d_ws;
  float*    WK2 = (float*)(w);
  unsigned* Urp = (unsigned*)(w + 1310720);
  unsigned* Uhp = (unsigned*)(w + 1441792);
  float*    qw1 = (float*)(w + 1572864);
  float*    qs  = (float*)(w + 1638400);
  float*    qe  = (float*)(w + 1638656);
  float*    att = (float*)(w + 1638912);
  float*    g   = (float*)(w + 1769984);
  unsigned* xrh = (unsigned*)(w + 1901056);
  unsigned short* ep = (unsigned short*)(w + 35455488);
  int*      mode = (int*)(w + 52232704);
  float* out = (float*)d_out;

  k_detect<<<dim3(1), dim3(256), 0, stream>>>(fact, mode);
  k_prep_w<<<dim3(256), dim3(256), 0, stream>>>(W1, Wr, Wh, Ur, Uh, mode, WK2, Urp, Uhp);
  k_prep_q<<<dim3(64), dim3(256), 0, stream>>>(q, W1, b1, Ws, bs, We, be, mode, qw1, qs, qe);
  k_main<<<dim3(2048), dim3(256), 0, stream>>>(fact, q, WK2, qw1, W2, b2v, br, bh, mode, att, xrh);
  k_softmax<<<dim3(64), dim3(512), 0, stream>>>(att, g);
  k_scan<<<dim3(64), dim3(1024), 0, stream>>>(Urp, Uhp, xrh, g, ilen, ep);
  k_out<<<dim3(8192), dim3(256), 0, stream>>>(ep, Ws, We, qs, qe, mode, out);
}